// Round 15
// baseline (132.908 us; speedup 1.0000x reference)
//
#include <hip/hip_runtime.h>
#include <math.h>

#define LSEQ 4096
#define DD 768
#define NST 16
#define RNK 48
#define TCH 32
#define NCH (LSEQ / TCH)   // 128 chunks
#define LTILE 8
#define NCOL 80            // 48 t + 32 bc
#define KSTEPS 24          // 768 / 32
#define NTILES 5           // 80 / 16
#define WFRAG_N (KSTEPS * NTILES * 64 * 8)   // 61440

typedef __attribute__((ext_vector_type(8))) short bf16x8;
typedef __attribute__((ext_vector_type(4))) float f32x4;

__device__ __forceinline__ float softplus_f(float z) {
    return fmaxf(z, 0.0f) + log1pf(expf(-fabsf(z)));
}

__device__ __forceinline__ float soft_clamp_f(float v) {
    const float ctr = 5.00005f;
    const float hr  = 4.99995f;
    const float inv_hr = 1.0f / 4.99995f;
    return ctr + hr * tanhf((v - ctr) * inv_hr);
}

__device__ __forceinline__ float wave_sum(float v) {
    #pragma unroll
    for (int m = 32; m >= 1; m >>= 1) v += __shfl_xor(v, m, 64);
    return v;
}

__device__ __forceinline__ unsigned short rne_bf16(float v) {
    unsigned u = __float_as_uint(v);
    return (unsigned short)((u + 0x7FFFu + ((u >> 16) & 1u)) >> 16);
}

// ---------------------------------------------------------------------------
// Prep: pack W (= [W_dt | W_bc], 768x80) into MFMA B-fragment order, bf16
// hi/lo. Index: ((kk*5 + n)*64 + lane)*8 + j holds W[32kk+(lane>>4)*8+j][16n+(lane&15)].
// ---------------------------------------------------------------------------
__global__ __launch_bounds__(256) void k_prep(
    const float* __restrict__ W_dt, const float* __restrict__ W_bc,
    unsigned short* __restrict__ wf_hi, unsigned short* __restrict__ wf_lo)
{
    int i = blockIdx.x * 256 + threadIdx.x;
    if (i >= WFRAG_N) return;
    int j  = i & 7;
    int l  = (i >> 3) & 63;
    int nk = i >> 9;
    int n  = nk % NTILES;
    int kk = nk / NTILES;
    int k   = kk * 32 + (l >> 4) * 8 + j;
    int col = n * 16 + (l & 15);
    float v = (col < RNK) ? W_dt[k * RNK + col] : W_bc[k * 32 + (col - RNK)];
    unsigned short h = rne_bf16(v);
    float hf = __uint_as_float((unsigned)h << 16);
    wf_hi[i] = h;
    wf_lo[i] = rne_bf16(v - hf);
}

// ---------------------------------------------------------------------------
// GEMM A (MFMA bf16 hi/lo): [4096x768]@[768x80] -> t[4096x48], bc[4096x32].
// 256 blocks x 1 wave; wave = 16-row M-tile x 5 N-tiles; K-loop 24 x 32.
// A layout: lane holds A[row=l&15][k=32kk+(l>>4)*8+j] (inline fp32->hi/lo).
// C/D layout (m89-verified): col=lane&15, row=(lane>>4)*4+reg.
// ---------------------------------------------------------------------------
__global__ __launch_bounds__(64) void k_gemmA(
    const float* __restrict__ x,
    const unsigned short* __restrict__ wf_hi,
    const unsigned short* __restrict__ wf_lo,
    float* __restrict__ tbuf, float* __restrict__ bc_out)
{
    const int lane = threadIdx.x;
    const int mt   = blockIdx.x;                // 0..255
    const int row  = mt * 16 + (lane & 15);
    const int ko   = (lane >> 4) * 8;

    f32x4 acc[NTILES];
    #pragma unroll
    for (int n = 0; n < NTILES; ++n) acc[n] = (f32x4){0.f, 0.f, 0.f, 0.f};

    #pragma unroll 2
    for (int kk = 0; kk < KSTEPS; ++kk) {
        const float* xp = x + (size_t)row * DD + kk * 32 + ko;
        float4 xa = *(const float4*)xp;
        float4 xb = *(const float4*)(xp + 4);
        float va[8] = {xa.x, xa.y, xa.z, xa.w, xb.x, xb.y, xb.z, xb.w};
        bf16x8 ah, al;
        #pragma unroll
        for (int j = 0; j < 8; ++j) {
            unsigned short h = rne_bf16(va[j]);
            float hf = __uint_as_float((unsigned)h << 16);
            ah[j] = (short)h;
            al[j] = (short)rne_bf16(va[j] - hf);
        }
        const int base = kk * (NTILES * 512) + lane * 8;
        #pragma unroll
        for (int n = 0; n < NTILES; ++n) {
            bf16x8 bh = *(const bf16x8*)(wf_hi + base + n * 512);
            bf16x8 bl = *(const bf16x8*)(wf_lo + base + n * 512);
            acc[n] = __builtin_amdgcn_mfma_f32_16x16x32_bf16(al, bh, acc[n], 0, 0, 0);
            acc[n] = __builtin_amdgcn_mfma_f32_16x16x32_bf16(ah, bl, acc[n], 0, 0, 0);
            acc[n] = __builtin_amdgcn_mfma_f32_16x16x32_bf16(ah, bh, acc[n], 0, 0, 0);
        }
    }

    const int r0 = mt * 16 + (lane >> 4) * 4;
    const int cb = lane & 15;
    #pragma unroll
    for (int n = 0; n < 3; ++n)
        #pragma unroll
        for (int r = 0; r < 4; ++r)
            tbuf[(size_t)(r0 + r) * RNK + n * 16 + cb] = acc[n][r];
    #pragma unroll
    for (int n = 3; n < 5; ++n)
        #pragma unroll
        for (int r = 0; r < 4; ++r)
            bc_out[(size_t)(r0 + r) * 32 + (n - 3) * 16 + cb] = acc[n][r];
}

// ---------------------------------------------------------------------------
// Proj B: delta = soft_clamp(rmsnorm(softplus(t @ W_dtp + b_dt)) * rms_scale)
// 512 blocks x 512 thr, 8 rows/block; t staged from tbuf (tiny LDS).
// ---------------------------------------------------------------------------
__global__ __launch_bounds__(512) void k_projB(
    const float* __restrict__ tbuf, const float* __restrict__ W_dtp,
    const float* __restrict__ b_dt, const float* __restrict__ rms_scale,
    float* __restrict__ delta_out)
{
    __shared__ __align__(16) float t_lds[LTILE][RNK];   // 1.5 KB
    __shared__ float red2[8][LTILE];

    const int tid = threadIdx.x;
    const int l0  = blockIdx.x * LTILE;

    if (tid < 96)
        *(float4*)&((float*)t_lds)[tid * 4] =
            *(const float4*)&tbuf[(size_t)l0 * RNK + tid * 4];
    __syncthreads();

    const int d0 = tid;
    const int d1 = tid + 512;
    const bool has2 = (tid < 256);

    float z0[LTILE], z1[LTILE];
    {
        float bb0 = b_dt[d0];
        float bb1 = has2 ? b_dt[d1] : 0.f;
        #pragma unroll
        for (int li = 0; li < LTILE; ++li) { z0[li] = bb0; z1[li] = bb1; }
    }
    #pragma unroll 2
    for (int r4 = 0; r4 < RNK; r4 += 4) {
        float w00 = W_dtp[(r4 + 0) * DD + d0];
        float w01 = W_dtp[(r4 + 1) * DD + d0];
        float w02 = W_dtp[(r4 + 2) * DD + d0];
        float w03 = W_dtp[(r4 + 3) * DD + d0];
        float w10 = has2 ? W_dtp[(r4 + 0) * DD + d1] : 0.f;
        float w11 = has2 ? W_dtp[(r4 + 1) * DD + d1] : 0.f;
        float w12 = has2 ? W_dtp[(r4 + 2) * DD + d1] : 0.f;
        float w13 = has2 ? W_dtp[(r4 + 3) * DD + d1] : 0.f;
        #pragma unroll
        for (int li = 0; li < LTILE; ++li) {
            float4 t4 = *(const float4*)&t_lds[li][r4];
            z0[li] = fmaf(t4.x, w00, z0[li]);
            z0[li] = fmaf(t4.y, w01, z0[li]);
            z0[li] = fmaf(t4.z, w02, z0[li]);
            z0[li] = fmaf(t4.w, w03, z0[li]);
            z1[li] = fmaf(t4.x, w10, z1[li]);
            z1[li] = fmaf(t4.y, w11, z1[li]);
            z1[li] = fmaf(t4.z, w12, z1[li]);
            z1[li] = fmaf(t4.w, w13, z1[li]);
        }
    }
    #pragma unroll
    for (int li = 0; li < LTILE; ++li) {
        z0[li] = softplus_f(z0[li]);
        z1[li] = has2 ? softplus_f(z1[li]) : 0.f;
    }
    const int wid = tid >> 6;
    const int lane = tid & 63;
    #pragma unroll
    for (int li = 0; li < LTILE; ++li) {
        float ss = wave_sum(z0[li] * z0[li] + z1[li] * z1[li]);
        if (lane == 0) red2[wid][li] = ss;
    }
    __syncthreads();
    {
        float rs0 = rms_scale[d0];
        float rs1 = has2 ? rms_scale[d1] : 0.f;
        #pragma unroll
        for (int li = 0; li < LTILE; ++li) {
            float tot = 0.f;
            #pragma unroll
            for (int k = 0; k < 8; ++k) tot += red2[k][li];
            float inv = rsqrtf(tot * (1.0f / DD) + 1e-6f);
            delta_out[(size_t)(l0 + li) * DD + d0] = soft_clamp_f(z0[li] * inv * rs0);
            if (has2)
                delta_out[(size_t)(l0 + li) * DD + d1] = soft_clamp_f(z1[li] * inv * rs1);
        }
    }
}

// ---------------------------------------------------------------------------
// Scan pass 1 (TCH=32, staged; sqrt(delta) in LDS; 1 rcp per step).
// ---------------------------------------------------------------------------
__global__ __launch_bounds__(256, 8) void k_scan1(
    const float* __restrict__ x, const float* __restrict__ delta,
    const float* __restrict__ bc, const float* __restrict__ A_log,
    float* __restrict__ Pbuf, float* __restrict__ Hbuf)
{
    __shared__ __align__(16) float xs[(TCH + 1) * 64];  // 8.25 KB
    __shared__ __align__(16) float sqv[TCH * 64];       // 8 KB
    __shared__ __align__(16) float bs[TCH * 16];        // 2 KB

    const int tid = threadIdx.x;
    const int db  = blockIdx.x * 64;
    const int c   = blockIdx.y;
    const int l0  = c * TCH;

    for (int i = tid; i < (TCH + 1) * 16; i += 256) {
        int r = i >> 4, f = i & 15;
        int l = l0 - 1 + r;
        float4 v = (l >= 0) ? *(const float4*)&x[(size_t)l * DD + db + f * 4]
                            : make_float4(0.f, 0.f, 0.f, 0.f);
        *(float4*)&xs[r * 64 + f * 4] = v;
    }
    for (int i = tid; i < TCH * 16; i += 256) {
        int r = i >> 4, f = i & 15;
        float4 v = *(const float4*)&delta[(size_t)(l0 + r) * DD + db + f * 4];
        v.x = sqrtf(v.x); v.y = sqrtf(v.y); v.z = sqrtf(v.z); v.w = sqrtf(v.w);
        *(float4*)&sqv[r * 64 + f * 4] = v;
    }
    if (tid < TCH * 4) {
        int r = tid >> 2, f = tid & 3;
        *(float4*)&bs[r * 16 + f * 4] =
            *(const float4*)&bc[(size_t)(l0 + r) * 32 + f * 4];
    }

    const int lane = tid & 63;
    const int w    = tid >> 6;
    const int q    = lane >> 4;
    const int dlo  = (lane & 15) + w * 16;
    const int d    = db + dlo;

    float An[4];
    {
        float4 a = *(const float4*)&A_log[d * NST + q * 4];
        An[0] = -expf(a.x); An[1] = -expf(a.y);
        An[2] = -expf(a.z); An[3] = -expf(a.w);
    }
    __syncthreads();

    float h[4]  = {0.f, 0.f, 0.f, 0.f};
    float Pp[4] = {1.f, 1.f, 1.f, 1.f};
    float xprev = xs[dlo];

    #pragma unroll 4
    for (int ll = 0; ll < TCH; ++ll) {
        float xv = xs[(ll + 1) * 64 + dlo];
        float sq = sqv[ll * 64 + dlo];
        float4 Bc = *(const float4*)&bs[ll * 16 + q * 4];

        float xin = 0.5f * (xv + xprev);
        xprev = xv;
        float c0 = 0.5f * sq * sq;
        float c1 = sq * xin;

        float dn0 = fmaf(-c0, An[0], 1.0f);
        float dn1 = fmaf(-c0, An[1], 1.0f);
        float dn2 = fmaf(-c0, An[2], 1.0f);
        float dn3 = fmaf(-c0, An[3], 1.0f);
        float m01 = dn0 * dn1, m23 = dn2 * dn3;
        float ip  = __builtin_amdgcn_rcpf(m01 * m23);
        float ip01 = ip * m23, ip23 = ip * m01;
        float iv0 = ip01 * dn1, iv1 = ip01 * dn0;
        float iv2 = ip23 * dn3, iv3 = ip23 * dn2;
        float t10 = 2.0f - dn0, t11 = 2.0f - dn1;
        float t12 = 2.0f - dn2, t13 = 2.0f - dn3;

        Pp[0] *= t10 * iv0;
        Pp[1] *= t11 * iv1;
        Pp[2] *= t12 * iv2;
        Pp[3] *= t13 * iv3;
        h[0] = fmaf(t10, h[0], c1 * Bc.x) * iv0;
        h[1] = fmaf(t11, h[1], c1 * Bc.y) * iv1;
        h[2] = fmaf(t12, h[2], c1 * Bc.z) * iv2;
        h[3] = fmaf(t13, h[3], c1 * Bc.w) * iv3;
    }
    #pragma unroll
    for (int n = 0; n < 4; ++n) {
        int idx = (c * NST + q * 4 + n) * DD + d;
        Pbuf[idx] = Pp[n];
        Hbuf[idx] = h[n];
    }
}

// ---------------------------------------------------------------------------
// Scan pass 2: serial thread-per-series, coalesced, 8-deep prefetch.
// ---------------------------------------------------------------------------
__global__ __launch_bounds__(64) void k_scan2(
    float* __restrict__ Pbuf, const float* __restrict__ Hbuf)
{
    const int s = blockIdx.x * 64 + threadIdx.x;
    const int d = s % DD;
    const int n = s / DD;
    const int stride = NST * DD;

    int idx = n * DD + d;
    int idx_pf = idx;
    float p[8], h[8];
    #pragma unroll
    for (int i = 0; i < 8; ++i) {
        p[i] = Pbuf[idx_pf];
        h[i] = Hbuf[idx_pf];
        idx_pf += stride;
    }

    float carry = 0.f;
    for (int g = 0; g < NCH / 8; ++g) {
        float pn[8], hn[8];
        if (g + 1 < NCH / 8) {
            #pragma unroll
            for (int i = 0; i < 8; ++i) {
                pn[i] = Pbuf[idx_pf];
                hn[i] = Hbuf[idx_pf];
                idx_pf += stride;
            }
        }
        #pragma unroll
        for (int i = 0; i < 8; ++i) {
            Pbuf[idx] = carry;
            carry = fmaf(p[i], carry, h[i]);
            idx += stride;
        }
        #pragma unroll
        for (int i = 0; i < 8; ++i) { p[i] = pn[i]; h[i] = hn[i]; }
    }
}

// ---------------------------------------------------------------------------
// Scan pass 3 (TCH=32, staged, sqrt-in-LDS, 1 rcp/step).
// ---------------------------------------------------------------------------
__global__ __launch_bounds__(256, 8) void k_scan3(
    const float* __restrict__ x, const float* __restrict__ delta,
    const float* __restrict__ bc, const float* __restrict__ A_log,
    const float* __restrict__ carryin, const float* __restrict__ D_param,
    float* __restrict__ out)
{
    __shared__ __align__(16) float xs[(TCH + 1) * 64];
    __shared__ __align__(16) float sqv[TCH * 64];
    __shared__ __align__(16) float bs[TCH * 32];

    const int tid = threadIdx.x;
    const int db  = blockIdx.x * 64;
    const int c   = blockIdx.y;
    const int l0  = c * TCH;

    for (int i = tid; i < (TCH + 1) * 16; i += 256) {
        int r = i >> 4, f = i & 15;
        int l = l0 - 1 + r;
        float4 v = (l >= 0) ? *(const float4*)&x[(size_t)l * DD + db + f * 4]
                            : make_float4(0.f, 0.f, 0.f, 0.f);
        *(float4*)&xs[r * 64 + f * 4] = v;
    }
    for (int i = tid; i < TCH * 16; i += 256) {
        int r = i >> 4, f = i & 15;
        float4 v = *(const float4*)&delta[(size_t)(l0 + r) * DD + db + f * 4];
        v.x = sqrtf(v.x); v.y = sqrtf(v.y); v.z = sqrtf(v.z); v.w = sqrtf(v.w);
        *(float4*)&sqv[r * 64 + f * 4] = v;
    }
    for (int i = tid; i < TCH * 8; i += 256) {
        int r = i >> 3, f = i & 7;
        *(float4*)&bs[r * 32 + f * 4] =
            *(const float4*)&bc[(size_t)(l0 + r) * 32 + f * 4];
    }

    const int lane = tid & 63;
    const int w    = tid >> 6;
    const int q    = lane >> 4;
    const int dlo  = (lane & 15) + w * 16;
    const int d    = db + dlo;

    float An[4];
    {
        float4 a = *(const float4*)&A_log[d * NST + q * 4];
        An[0] = -expf(a.x); An[1] = -expf(a.y);
        An[2] = -expf(a.z); An[3] = -expf(a.w);
    }
    float h[4];
    #pragma unroll
    for (int n = 0; n < 4; ++n)
        h[n] = carryin[(c * NST + q * 4 + n) * DD + d];
    const float Dp = D_param[d];

    __syncthreads();

    float xprev = xs[dlo];
    #pragma unroll 4
    for (int ll = 0; ll < TCH; ++ll) {
        float xv = xs[(ll + 1) * 64 + dlo];
        float sq = sqv[ll * 64 + dlo];
        float4 Bc = *(const float4*)&bs[ll * 32 + q * 4];
        float4 Cc = *(const float4*)&bs[ll * 32 + 16 + q * 4];

        float xin = 0.5f * (xv + xprev);
        xprev = xv;
        float c0 = 0.5f * sq * sq;
        float c1 = sq * xin;

        float dn0 = fmaf(-c0, An[0], 1.0f);
        float dn1 = fmaf(-c0, An[1], 1.0f);
        float dn2 = fmaf(-c0, An[2], 1.0f);
        float dn3 = fmaf(-c0, An[3], 1.0f);
        float m01 = dn0 * dn1, m23 = dn2 * dn3;
        float ip  = __builtin_amdgcn_rcpf(m01 * m23);
        float ip01 = ip * m23, ip23 = ip * m01;
        float iv0 = ip01 * dn1, iv1 = ip01 * dn0;
        float iv2 = ip23 * dn3, iv3 = ip23 * dn2;
        float t10 = 2.0f - dn0, t11 = 2.0f - dn1;
        float t12 = 2.0f - dn2, t13 = 2.0f - dn3;

        h[0] = fmaf(t10, h[0], c1 * Bc.x) * iv0;
        h[1] = fmaf(t11, h[1], c1 * Bc.y) * iv1;
        h[2] = fmaf(t12, h[2], c1 * Bc.z) * iv2;
        h[3] = fmaf(t13, h[3], c1 * Bc.w) * iv3;

        float y = h[0] * Cc.x;
        y = fmaf(h[1], Cc.y, y);
        y = fmaf(h[2], Cc.z, y);
        y = fmaf(h[3], Cc.w, y);

        y += __shfl_xor(y, 16, 64);
        y += __shfl_xor(y, 32, 64);
        if (q == 0)
            out[(size_t)(l0 + ll) * DD + d] = fmaf(Dp, xv, y);
    }
}

extern "C" void kernel_launch(void* const* d_in, const int* in_sizes, int n_in,
                              void* d_out, int out_size, void* d_ws, size_t ws_size,
                              hipStream_t stream) {
    const float* x         = (const float*)d_in[0];
    const float* A_log     = (const float*)d_in[1];
    const float* D_param   = (const float*)d_in[2];
    const float* W_bc      = (const float*)d_in[3];
    const float* W_dt      = (const float*)d_in[4];
    const float* W_dtp     = (const float*)d_in[5];
    const float* b_dt      = (const float*)d_in[6];
    const float* rms_scale = (const float*)d_in[7];
    float* out = (float*)d_out;

    float* ws    = (float*)d_ws;
    float* delta = ws;                               // L*D          = 3,145,728
    float* bcbuf = delta + (size_t)LSEQ * DD;        // L*32         =   131,072
    float* Pbuf  = bcbuf + (size_t)LSEQ * 32;        // NCH*16*D     = 1,572,864
    float* Hbuf  = Pbuf + (size_t)NCH * NST * DD;    // NCH*16*D     = 1,572,864
    float* tbuf  = Hbuf + (size_t)NCH * NST * DD;    // L*48         =   196,608
    unsigned short* wf_hi = (unsigned short*)(tbuf + (size_t)LSEQ * RNK);
    unsigned short* wf_lo = wf_hi + WFRAG_N;

    k_prep<<<(WFRAG_N + 255) / 256, 256, 0, stream>>>(W_dt, W_bc, wf_hi, wf_lo);
    k_gemmA<<<LSEQ / 16, 64, 0, stream>>>(x, wf_hi, wf_lo, tbuf, bcbuf);
    k_projB<<<LSEQ / LTILE, 512, 0, stream>>>(tbuf, W_dtp, b_dt, rms_scale, delta);
    k_scan1<<<dim3(DD / 64, NCH), 256, 0, stream>>>(x, delta, bcbuf, A_log,
                                                    Pbuf, Hbuf);
    k_scan2<<<(DD * NST) / 64, 64, 0, stream>>>(Pbuf, Hbuf);
    k_scan3<<<dim3(DD / 64, NCH), 256, 0, stream>>>(x, delta, bcbuf, A_log,
                                                    Pbuf, D_param, out);
}

// Round 16
// 92.331 us; speedup vs baseline: 1.4395x; 1.4395x over previous
//
#include <hip/hip_runtime.h>
#include <math.h>

#define LSEQ 4096
#define DD 768
#define NST 16
#define RNK 48
#define TCH 32
#define NCH (LSEQ / TCH)   // 128 chunks
#define LTILE 8
#define NCOL 80            // 48 t + 32 bc
#define KSTEPS 24          // 768 / 32
#define NTILES 5           // 80 / 16
#define WFRAG_N (KSTEPS * NTILES * 64 * 8)   // 61440

typedef __attribute__((ext_vector_type(8))) short bf16x8;
typedef __attribute__((ext_vector_type(4))) float f32x4;

__device__ __forceinline__ float softplus_f(float z) {
    return fmaxf(z, 0.0f) + log1pf(expf(-fabsf(z)));
}

__device__ __forceinline__ float soft_clamp_f(float v) {
    const float ctr = 5.00005f;
    const float hr  = 4.99995f;
    const float inv_hr = 1.0f / 4.99995f;
    return ctr + hr * tanhf((v - ctr) * inv_hr);
}

__device__ __forceinline__ float wave_sum(float v) {
    #pragma unroll
    for (int m = 32; m >= 1; m >>= 1) v += __shfl_xor(v, m, 64);
    return v;
}

__device__ __forceinline__ unsigned short rne_bf16(float v) {
    unsigned u = __float_as_uint(v);
    return (unsigned short)((u + 0x7FFFu + ((u >> 16) & 1u)) >> 16);
}

// ---------------------------------------------------------------------------
// Prep: pack W (= [W_dt | W_bc], 768x80) into MFMA B-fragment order, bf16
// hi/lo. Index: ((kk*5+n)*64+lane)*8+j holds W[32kk+(lane>>4)*8+j][16n+(lane&15)].
// ---------------------------------------------------------------------------
__global__ __launch_bounds__(256) void k_prep(
    const float* __restrict__ W_dt, const float* __restrict__ W_bc,
    unsigned short* __restrict__ wf_hi, unsigned short* __restrict__ wf_lo)
{
    int i = blockIdx.x * 256 + threadIdx.x;
    if (i >= WFRAG_N) return;
    int j  = i & 7;
    int l  = (i >> 3) & 63;
    int nk = i >> 9;
    int n  = nk % NTILES;
    int kk = nk / NTILES;
    int k   = kk * 32 + (l >> 4) * 8 + j;
    int col = n * 16 + (l & 15);
    float v = (col < RNK) ? W_dt[k * RNK + col] : W_bc[k * 32 + (col - RNK)];
    unsigned short h = rne_bf16(v);
    float hf = __uint_as_float((unsigned)h << 16);
    wf_hi[i] = h;
    wf_lo[i] = rne_bf16(v - hf);
}

// ---------------------------------------------------------------------------
// GEMM A v2 (MFMA bf16 hi/lo, latency-fixed): 256 blocks x 4 waves.
// Block = one 16-row M-tile; x staged coalesced into LDS; K split 4-way
// across waves (6 K-steps each); partials reduced via reused LDS.
// C/D mapping (m89-verified): col=lane&15, row=(lane>>4)*4+reg.
// ---------------------------------------------------------------------------
__global__ __launch_bounds__(256) void k_gemmA(
    const float* __restrict__ x,
    const unsigned short* __restrict__ wf_hi,
    const unsigned short* __restrict__ wf_lo,
    float* __restrict__ tbuf, float* __restrict__ bc_out)
{
    __shared__ __align__(16) float smem[16 * 772];   // 49.4 KB; reused for red

    const int tid  = threadIdx.x;
    const int lane = tid & 63;
    const int wq   = tid >> 6;          // K-slice 0..3
    const int mt   = blockIdx.x;

    // stage 16 rows = 12288 contiguous floats, coalesced
    {
        const float4* xg = (const float4*)(x + (size_t)mt * 16 * DD);
        #pragma unroll 4
        for (int idx = tid; idx < 3072; idx += 256) {
            int r = idx / 192, c4 = idx - r * 192;
            *(float4*)&smem[r * 772 + c4 * 4] = xg[idx];
        }
    }
    __syncthreads();

    const int rloc = lane & 15;
    const int ko   = (lane >> 4) * 8;

    f32x4 acc[NTILES];
    #pragma unroll
    for (int n = 0; n < NTILES; ++n) acc[n] = (f32x4){0.f, 0.f, 0.f, 0.f};

    #pragma unroll
    for (int k6 = 0; k6 < 6; ++k6) {
        const int kk = wq * 6 + k6;
        const float* xp = &smem[rloc * 772 + kk * 32 + ko];
        float4 xa = *(const float4*)xp;
        float4 xb = *(const float4*)(xp + 4);
        float va[8] = {xa.x, xa.y, xa.z, xa.w, xb.x, xb.y, xb.z, xb.w};
        bf16x8 ah, al;
        #pragma unroll
        for (int j = 0; j < 8; ++j) {
            unsigned short h = rne_bf16(va[j]);
            float hf = __uint_as_float((unsigned)h << 16);
            ah[j] = (short)h;
            al[j] = (short)rne_bf16(va[j] - hf);
        }
        const int base = kk * (NTILES * 512) + lane * 8;
        #pragma unroll
        for (int n = 0; n < NTILES; ++n) {
            bf16x8 bh = *(const bf16x8*)(wf_hi + base + n * 512);
            bf16x8 bl = *(const bf16x8*)(wf_lo + base + n * 512);
            acc[n] = __builtin_amdgcn_mfma_f32_16x16x32_bf16(al, bh, acc[n], 0, 0, 0);
            acc[n] = __builtin_amdgcn_mfma_f32_16x16x32_bf16(ah, bl, acc[n], 0, 0, 0);
            acc[n] = __builtin_amdgcn_mfma_f32_16x16x32_bf16(ah, bh, acc[n], 0, 0, 0);
        }
    }
    __syncthreads();   // all LDS x-reads done; smem reusable

    // reduce partials: waves 1..3 dump to LDS, wave 0 sums + writes out
    if (wq > 0) {
        float* red = smem + ((wq - 1) * 64 + lane) * 20;
        #pragma unroll
        for (int n = 0; n < NTILES; ++n)
            #pragma unroll
            for (int r = 0; r < 4; ++r) red[n * 4 + r] = acc[n][r];
    }
    __syncthreads();
    if (wq == 0) {
        #pragma unroll
        for (int w = 0; w < 3; ++w) {
            const float* red = smem + (w * 64 + lane) * 20;
            #pragma unroll
            for (int n = 0; n < NTILES; ++n)
                #pragma unroll
                for (int r = 0; r < 4; ++r) acc[n][r] += red[n * 4 + r];
        }
        const int r0 = mt * 16 + (lane >> 4) * 4;
        const int cb = lane & 15;
        #pragma unroll
        for (int n = 0; n < 3; ++n)
            #pragma unroll
            for (int r = 0; r < 4; ++r)
                tbuf[(size_t)(r0 + r) * RNK + n * 16 + cb] = acc[n][r];
        #pragma unroll
        for (int n = 3; n < 5; ++n)
            #pragma unroll
            for (int r = 0; r < 4; ++r)
                bc_out[(size_t)(r0 + r) * 32 + (n - 3) * 16 + cb] = acc[n][r];
    }
}

// ---------------------------------------------------------------------------
// Proj B: delta = soft_clamp(rmsnorm(softplus(t @ W_dtp + b_dt)) * rms_scale)
// ---------------------------------------------------------------------------
__global__ __launch_bounds__(512) void k_projB(
    const float* __restrict__ tbuf, const float* __restrict__ W_dtp,
    const float* __restrict__ b_dt, const float* __restrict__ rms_scale,
    float* __restrict__ delta_out)
{
    __shared__ __align__(16) float t_lds[LTILE][RNK];   // 1.5 KB
    __shared__ float red2[8][LTILE];

    const int tid = threadIdx.x;
    const int l0  = blockIdx.x * LTILE;

    if (tid < 96)
        *(float4*)&((float*)t_lds)[tid * 4] =
            *(const float4*)&tbuf[(size_t)l0 * RNK + tid * 4];
    __syncthreads();

    const int d0 = tid;
    const int d1 = tid + 512;
    const bool has2 = (tid < 256);

    float z0[LTILE], z1[LTILE];
    {
        float bb0 = b_dt[d0];
        float bb1 = has2 ? b_dt[d1] : 0.f;
        #pragma unroll
        for (int li = 0; li < LTILE; ++li) { z0[li] = bb0; z1[li] = bb1; }
    }
    #pragma unroll 2
    for (int r4 = 0; r4 < RNK; r4 += 4) {
        float w00 = W_dtp[(r4 + 0) * DD + d0];
        float w01 = W_dtp[(r4 + 1) * DD + d0];
        float w02 = W_dtp[(r4 + 2) * DD + d0];
        float w03 = W_dtp[(r4 + 3) * DD + d0];
        float w10 = has2 ? W_dtp[(r4 + 0) * DD + d1] : 0.f;
        float w11 = has2 ? W_dtp[(r4 + 1) * DD + d1] : 0.f;
        float w12 = has2 ? W_dtp[(r4 + 2) * DD + d1] : 0.f;
        float w13 = has2 ? W_dtp[(r4 + 3) * DD + d1] : 0.f;
        #pragma unroll
        for (int li = 0; li < LTILE; ++li) {
            float4 t4 = *(const float4*)&t_lds[li][r4];
            z0[li] = fmaf(t4.x, w00, z0[li]);
            z0[li] = fmaf(t4.y, w01, z0[li]);
            z0[li] = fmaf(t4.z, w02, z0[li]);
            z0[li] = fmaf(t4.w, w03, z0[li]);
            z1[li] = fmaf(t4.x, w10, z1[li]);
            z1[li] = fmaf(t4.y, w11, z1[li]);
            z1[li] = fmaf(t4.z, w12, z1[li]);
            z1[li] = fmaf(t4.w, w13, z1[li]);
        }
    }
    #pragma unroll
    for (int li = 0; li < LTILE; ++li) {
        z0[li] = softplus_f(z0[li]);
        z1[li] = has2 ? softplus_f(z1[li]) : 0.f;
    }
    const int wid = tid >> 6;
    const int lane = tid & 63;
    #pragma unroll
    for (int li = 0; li < LTILE; ++li) {
        float ss = wave_sum(z0[li] * z0[li] + z1[li] * z1[li]);
        if (lane == 0) red2[wid][li] = ss;
    }
    __syncthreads();
    {
        float rs0 = rms_scale[d0];
        float rs1 = has2 ? rms_scale[d1] : 0.f;
        #pragma unroll
        for (int li = 0; li < LTILE; ++li) {
            float tot = 0.f;
            #pragma unroll
            for (int k = 0; k < 8; ++k) tot += red2[k][li];
            float inv = rsqrtf(tot * (1.0f / DD) + 1e-6f);
            delta_out[(size_t)(l0 + li) * DD + d0] = soft_clamp_f(z0[li] * inv * rs0);
            if (has2)
                delta_out[(size_t)(l0 + li) * DD + d1] = soft_clamp_f(z1[li] * inv * rs1);
        }
    }
}

// ---------------------------------------------------------------------------
// Scan pass 1 (TCH=32, staged; sqrt(delta) in LDS; 1 rcp per step).
// ---------------------------------------------------------------------------
__global__ __launch_bounds__(256, 8) void k_scan1(
    const float* __restrict__ x, const float* __restrict__ delta,
    const float* __restrict__ bc, const float* __restrict__ A_log,
    float* __restrict__ Pbuf, float* __restrict__ Hbuf)
{
    __shared__ __align__(16) float xs[(TCH + 1) * 64];  // 8.25 KB
    __shared__ __align__(16) float sqv[TCH * 64];       // 8 KB
    __shared__ __align__(16) float bs[TCH * 16];        // 2 KB

    const int tid = threadIdx.x;
    const int db  = blockIdx.x * 64;
    const int c   = blockIdx.y;
    const int l0  = c * TCH;

    for (int i = tid; i < (TCH + 1) * 16; i += 256) {
        int r = i >> 4, f = i & 15;
        int l = l0 - 1 + r;
        float4 v = (l >= 0) ? *(const float4*)&x[(size_t)l * DD + db + f * 4]
                            : make_float4(0.f, 0.f, 0.f, 0.f);
        *(float4*)&xs[r * 64 + f * 4] = v;
    }
    for (int i = tid; i < TCH * 16; i += 256) {
        int r = i >> 4, f = i & 15;
        float4 v = *(const float4*)&delta[(size_t)(l0 + r) * DD + db + f * 4];
        v.x = sqrtf(v.x); v.y = sqrtf(v.y); v.z = sqrtf(v.z); v.w = sqrtf(v.w);
        *(float4*)&sqv[r * 64 + f * 4] = v;
    }
    if (tid < TCH * 4) {
        int r = tid >> 2, f = tid & 3;
        *(float4*)&bs[r * 16 + f * 4] =
            *(const float4*)&bc[(size_t)(l0 + r) * 32 + f * 4];
    }

    const int lane = tid & 63;
    const int w    = tid >> 6;
    const int q    = lane >> 4;
    const int dlo  = (lane & 15) + w * 16;
    const int d    = db + dlo;

    float An[4];
    {
        float4 a = *(const float4*)&A_log[d * NST + q * 4];
        An[0] = -expf(a.x); An[1] = -expf(a.y);
        An[2] = -expf(a.z); An[3] = -expf(a.w);
    }
    __syncthreads();

    float h[4]  = {0.f, 0.f, 0.f, 0.f};
    float Pp[4] = {1.f, 1.f, 1.f, 1.f};
    float xprev = xs[dlo];

    #pragma unroll 4
    for (int ll = 0; ll < TCH; ++ll) {
        float xv = xs[(ll + 1) * 64 + dlo];
        float sq = sqv[ll * 64 + dlo];
        float4 Bc = *(const float4*)&bs[ll * 16 + q * 4];

        float xin = 0.5f * (xv + xprev);
        xprev = xv;
        float c0 = 0.5f * sq * sq;
        float c1 = sq * xin;

        float dn0 = fmaf(-c0, An[0], 1.0f);
        float dn1 = fmaf(-c0, An[1], 1.0f);
        float dn2 = fmaf(-c0, An[2], 1.0f);
        float dn3 = fmaf(-c0, An[3], 1.0f);
        float m01 = dn0 * dn1, m23 = dn2 * dn3;
        float ip  = __builtin_amdgcn_rcpf(m01 * m23);
        float ip01 = ip * m23, ip23 = ip * m01;
        float iv0 = ip01 * dn1, iv1 = ip01 * dn0;
        float iv2 = ip23 * dn3, iv3 = ip23 * dn2;
        float t10 = 2.0f - dn0, t11 = 2.0f - dn1;
        float t12 = 2.0f - dn2, t13 = 2.0f - dn3;

        Pp[0] *= t10 * iv0;
        Pp[1] *= t11 * iv1;
        Pp[2] *= t12 * iv2;
        Pp[3] *= t13 * iv3;
        h[0] = fmaf(t10, h[0], c1 * Bc.x) * iv0;
        h[1] = fmaf(t11, h[1], c1 * Bc.y) * iv1;
        h[2] = fmaf(t12, h[2], c1 * Bc.z) * iv2;
        h[3] = fmaf(t13, h[3], c1 * Bc.w) * iv3;
    }
    #pragma unroll
    for (int n = 0; n < 4; ++n) {
        int idx = (c * NST + q * 4 + n) * DD + d;
        Pbuf[idx] = Pp[n];
        Hbuf[idx] = h[n];
    }
}

// ---------------------------------------------------------------------------
// Scan pass 2: serial thread-per-series, coalesced, 8-deep prefetch.
// ---------------------------------------------------------------------------
__global__ __launch_bounds__(64) void k_scan2(
    float* __restrict__ Pbuf, const float* __restrict__ Hbuf)
{
    const int s = blockIdx.x * 64 + threadIdx.x;
    const int d = s % DD;
    const int n = s / DD;
    const int stride = NST * DD;

    int idx = n * DD + d;
    int idx_pf = idx;
    float p[8], h[8];
    #pragma unroll
    for (int i = 0; i < 8; ++i) {
        p[i] = Pbuf[idx_pf];
        h[i] = Hbuf[idx_pf];
        idx_pf += stride;
    }

    float carry = 0.f;
    for (int g = 0; g < NCH / 8; ++g) {
        float pn[8], hn[8];
        if (g + 1 < NCH / 8) {
            #pragma unroll
            for (int i = 0; i < 8; ++i) {
                pn[i] = Pbuf[idx_pf];
                hn[i] = Hbuf[idx_pf];
                idx_pf += stride;
            }
        }
        #pragma unroll
        for (int i = 0; i < 8; ++i) {
            Pbuf[idx] = carry;
            carry = fmaf(p[i], carry, h[i]);
            idx += stride;
        }
        #pragma unroll
        for (int i = 0; i < 8; ++i) { p[i] = pn[i]; h[i] = hn[i]; }
    }
}

// ---------------------------------------------------------------------------
// Scan pass 3 (TCH=32, staged, sqrt-in-LDS, 1 rcp/step).
// ---------------------------------------------------------------------------
__global__ __launch_bounds__(256, 8) void k_scan3(
    const float* __restrict__ x, const float* __restrict__ delta,
    const float* __restrict__ bc, const float* __restrict__ A_log,
    const float* __restrict__ carryin, const float* __restrict__ D_param,
    float* __restrict__ out)
{
    __shared__ __align__(16) float xs[(TCH + 1) * 64];
    __shared__ __align__(16) float sqv[TCH * 64];
    __shared__ __align__(16) float bs[TCH * 32];

    const int tid = threadIdx.x;
    const int db  = blockIdx.x * 64;
    const int c   = blockIdx.y;
    const int l0  = c * TCH;

    for (int i = tid; i < (TCH + 1) * 16; i += 256) {
        int r = i >> 4, f = i & 15;
        int l = l0 - 1 + r;
        float4 v = (l >= 0) ? *(const float4*)&x[(size_t)l * DD + db + f * 4]
                            : make_float4(0.f, 0.f, 0.f, 0.f);
        *(float4*)&xs[r * 64 + f * 4] = v;
    }
    for (int i = tid; i < TCH * 16; i += 256) {
        int r = i >> 4, f = i & 15;
        float4 v = *(const float4*)&delta[(size_t)(l0 + r) * DD + db + f * 4];
        v.x = sqrtf(v.x); v.y = sqrtf(v.y); v.z = sqrtf(v.z); v.w = sqrtf(v.w);
        *(float4*)&sqv[r * 64 + f * 4] = v;
    }
    for (int i = tid; i < TCH * 8; i += 256) {
        int r = i >> 3, f = i & 7;
        *(float4*)&bs[r * 32 + f * 4] =
            *(const float4*)&bc[(size_t)(l0 + r) * 32 + f * 4];
    }

    const int lane = tid & 63;
    const int w    = tid >> 6;
    const int q    = lane >> 4;
    const int dlo  = (lane & 15) + w * 16;
    const int d    = db + dlo;

    float An[4];
    {
        float4 a = *(const float4*)&A_log[d * NST + q * 4];
        An[0] = -expf(a.x); An[1] = -expf(a.y);
        An[2] = -expf(a.z); An[3] = -expf(a.w);
    }
    float h[4];
    #pragma unroll
    for (int n = 0; n < 4; ++n)
        h[n] = carryin[(c * NST + q * 4 + n) * DD + d];
    const float Dp = D_param[d];

    __syncthreads();

    float xprev = xs[dlo];
    #pragma unroll 4
    for (int ll = 0; ll < TCH; ++ll) {
        float xv = xs[(ll + 1) * 64 + dlo];
        float sq = sqv[ll * 64 + dlo];
        float4 Bc = *(const float4*)&bs[ll * 32 + q * 4];
        float4 Cc = *(const float4*)&bs[ll * 32 + 16 + q * 4];

        float xin = 0.5f * (xv + xprev);
        xprev = xv;
        float c0 = 0.5f * sq * sq;
        float c1 = sq * xin;

        float dn0 = fmaf(-c0, An[0], 1.0f);
        float dn1 = fmaf(-c0, An[1], 1.0f);
        float dn2 = fmaf(-c0, An[2], 1.0f);
        float dn3 = fmaf(-c0, An[3], 1.0f);
        float m01 = dn0 * dn1, m23 = dn2 * dn3;
        float ip  = __builtin_amdgcn_rcpf(m01 * m23);
        float ip01 = ip * m23, ip23 = ip * m01;
        float iv0 = ip01 * dn1, iv1 = ip01 * dn0;
        float iv2 = ip23 * dn3, iv3 = ip23 * dn2;
        float t10 = 2.0f - dn0, t11 = 2.0f - dn1;
        float t12 = 2.0f - dn2, t13 = 2.0f - dn3;

        h[0] = fmaf(t10, h[0], c1 * Bc.x) * iv0;
        h[1] = fmaf(t11, h[1], c1 * Bc.y) * iv1;
        h[2] = fmaf(t12, h[2], c1 * Bc.z) * iv2;
        h[3] = fmaf(t13, h[3], c1 * Bc.w) * iv3;

        float y = h[0] * Cc.x;
        y = fmaf(h[1], Cc.y, y);
        y = fmaf(h[2], Cc.z, y);
        y = fmaf(h[3], Cc.w, y);

        y += __shfl_xor(y, 16, 64);
        y += __shfl_xor(y, 32, 64);
        if (q == 0)
            out[(size_t)(l0 + ll) * DD + d] = fmaf(Dp, xv, y);
    }
}

extern "C" void kernel_launch(void* const* d_in, const int* in_sizes, int n_in,
                              void* d_out, int out_size, void* d_ws, size_t ws_size,
                              hipStream_t stream) {
    const float* x         = (const float*)d_in[0];
    const float* A_log     = (const float*)d_in[1];
    const float* D_param   = (const float*)d_in[2];
    const float* W_bc      = (const float*)d_in[3];
    const float* W_dt      = (const float*)d_in[4];
    const float* W_dtp     = (const float*)d_in[5];
    const float* b_dt      = (const float*)d_in[6];
    const float* rms_scale = (const float*)d_in[7];
    float* out = (float*)d_out;

    float* ws    = (float*)d_ws;
    float* delta = ws;                               // L*D
    float* bcbuf = delta + (size_t)LSEQ * DD;        // L*32
    float* Pbuf  = bcbuf + (size_t)LSEQ * 32;        // NCH*16*D
    float* Hbuf  = Pbuf + (size_t)NCH * NST * DD;    // NCH*16*D
    float* tbuf  = Hbuf + (size_t)NCH * NST * DD;    // L*48
    unsigned short* wf_hi = (unsigned short*)(tbuf + (size_t)LSEQ * RNK);
    unsigned short* wf_lo = wf_hi + WFRAG_N;

    k_prep<<<(WFRAG_N + 255) / 256, 256, 0, stream>>>(W_dt, W_bc, wf_hi, wf_lo);
    k_gemmA<<<LSEQ / 16, 256, 0, stream>>>(x, wf_hi, wf_lo, tbuf, bcbuf);
    k_projB<<<LSEQ / LTILE, 512, 0, stream>>>(tbuf, W_dtp, b_dt, rms_scale, delta);
    k_scan1<<<dim3(DD / 64, NCH), 256, 0, stream>>>(x, delta, bcbuf, A_log,
                                                    Pbuf, Hbuf);
    k_scan2<<<(DD * NST) / 64, 64, 0, stream>>>(Pbuf, Hbuf);
    k_scan3<<<dim3(DD / 64, NCH), 256, 0, stream>>>(x, delta, bcbuf, A_log,
                                                    Pbuf, D_param, out);
}

// Round 17
// 89.856 us; speedup vs baseline: 1.4791x; 1.0275x over previous
//
#include <hip/hip_runtime.h>
#include <math.h>

#define LSEQ 4096
#define DD 768
#define NST 16
#define RNK 48
#define TCH 32
#define NCH (LSEQ / TCH)   // 128 chunks
#define KSTEPS 24          // 768 / 32
#define NTILES 5           // 80 / 16
#define WFRAG_N (KSTEPS * NTILES * 64 * 8)   // 61440

typedef __attribute__((ext_vector_type(8))) short bf16x8;
typedef __attribute__((ext_vector_type(4))) float f32x4;

__device__ __forceinline__ float softplus_f(float z) {
    return fmaxf(z, 0.0f) + log1pf(expf(-fabsf(z)));
}

__device__ __forceinline__ float soft_clamp_f(float v) {
    const float ctr = 5.00005f;
    const float hr  = 4.99995f;
    const float inv_hr = 1.0f / 4.99995f;
    return ctr + hr * tanhf((v - ctr) * inv_hr);
}

__device__ __forceinline__ float wave_sum(float v) {
    #pragma unroll
    for (int m = 32; m >= 1; m >>= 1) v += __shfl_xor(v, m, 64);
    return v;
}

__device__ __forceinline__ unsigned short rne_bf16(float v) {
    unsigned u = __float_as_uint(v);
    return (unsigned short)((u + 0x7FFFu + ((u >> 16) & 1u)) >> 16);
}

// ---------------------------------------------------------------------------
// Prep: pack W (= [W_dt | W_bc], 768x80) into MFMA B-fragment order, bf16
// hi/lo. Index: ((kk*5+n)*64+lane)*8+j holds W[32kk+(lane>>4)*8+j][16n+(lane&15)].
// ---------------------------------------------------------------------------
__global__ __launch_bounds__(256) void k_prep(
    const float* __restrict__ W_dt, const float* __restrict__ W_bc,
    unsigned short* __restrict__ wf_hi, unsigned short* __restrict__ wf_lo)
{
    int i = blockIdx.x * 256 + threadIdx.x;
    if (i >= WFRAG_N) return;
    int j  = i & 7;
    int l  = (i >> 3) & 63;
    int nk = i >> 9;
    int n  = nk % NTILES;
    int kk = nk / NTILES;
    int k   = kk * 32 + (l >> 4) * 8 + j;
    int col = n * 16 + (l & 15);
    float v = (col < RNK) ? W_dt[k * RNK + col] : W_bc[k * 32 + (col - RNK)];
    unsigned short h = rne_bf16(v);
    float hf = __uint_as_float((unsigned)h << 16);
    wf_hi[i] = h;
    wf_lo[i] = rne_bf16(v - hf);
}

// ---------------------------------------------------------------------------
// Fused proj (MFMA phase A + phase B): 256 blocks x 8 waves.
// Block = 16-row M-tile. Stage x -> MFMA K-loop (K split 8-way) -> partial
// reduce in reused LDS -> t kept in LDS (3 KB) + bc to global -> phase B
// (z = t@W_dtp + b, softplus, block-local RMS over the full 768-d row,
// soft_clamp) -> delta. No tbuf round-trip, no extra launches.
// C/D mapping (m89-verified): col=lane&15, row=(lane>>4)*4+reg.
// ---------------------------------------------------------------------------
__global__ __launch_bounds__(512) void k_proj_mfma(
    const float* __restrict__ x,
    const unsigned short* __restrict__ wf_hi,
    const unsigned short* __restrict__ wf_lo,
    const float* __restrict__ W_dtp, const float* __restrict__ b_dt,
    const float* __restrict__ rms_scale,
    float* __restrict__ delta_out, float* __restrict__ bc_out)
{
    __shared__ __align__(16) float smem[16 * 772];   // 49.4 KB; x then partials
    __shared__ __align__(16) float t_lds[16][RNK];   // 3 KB
    __shared__ float red2[8][16];

    const int tid  = threadIdx.x;
    const int lane = tid & 63;
    const int wq   = tid >> 6;          // wave 0..7 = K-slice
    const int mt   = blockIdx.x;

    // stage 16 rows (contiguous in global), coalesced
    {
        const float4* xg = (const float4*)(x + (size_t)mt * 16 * DD);
        #pragma unroll 2
        for (int idx = tid; idx < 3072; idx += 512) {
            int r = idx / 192, c4 = idx - r * 192;
            *(float4*)&smem[r * 772 + c4 * 4] = xg[idx];
        }
    }
    __syncthreads();

    const int rloc = lane & 15;
    const int ko   = (lane >> 4) * 8;

    f32x4 acc[NTILES];
    #pragma unroll
    for (int n = 0; n < NTILES; ++n) acc[n] = (f32x4){0.f, 0.f, 0.f, 0.f};

    #pragma unroll
    for (int k3 = 0; k3 < 3; ++k3) {
        const int kk = wq * 3 + k3;
        const float* xp = &smem[rloc * 772 + kk * 32 + ko];
        float4 xa = *(const float4*)xp;
        float4 xb = *(const float4*)(xp + 4);
        float va[8] = {xa.x, xa.y, xa.z, xa.w, xb.x, xb.y, xb.z, xb.w};
        bf16x8 ah, al;
        #pragma unroll
        for (int j = 0; j < 8; ++j) {
            unsigned short h = rne_bf16(va[j]);
            float hf = __uint_as_float((unsigned)h << 16);
            ah[j] = (short)h;
            al[j] = (short)rne_bf16(va[j] - hf);
        }
        const int base = kk * (NTILES * 512) + lane * 8;
        #pragma unroll
        for (int n = 0; n < NTILES; ++n) {
            bf16x8 bh = *(const bf16x8*)(wf_hi + base + n * 512);
            bf16x8 bl = *(const bf16x8*)(wf_lo + base + n * 512);
            acc[n] = __builtin_amdgcn_mfma_f32_16x16x32_bf16(al, bh, acc[n], 0, 0, 0);
            acc[n] = __builtin_amdgcn_mfma_f32_16x16x32_bf16(ah, bl, acc[n], 0, 0, 0);
            acc[n] = __builtin_amdgcn_mfma_f32_16x16x32_bf16(ah, bh, acc[n], 0, 0, 0);
        }
    }
    __syncthreads();   // x reads done; smem reusable for partials

    if (wq > 0) {
        float* red = smem + ((wq - 1) * 64 + lane) * 20;
        #pragma unroll
        for (int n = 0; n < NTILES; ++n)
            #pragma unroll
            for (int r = 0; r < 4; ++r) red[n * 4 + r] = acc[n][r];
    }
    __syncthreads();
    if (wq == 0) {
        #pragma unroll
        for (int w = 0; w < 7; ++w) {
            const float* red = smem + (w * 64 + lane) * 20;
            #pragma unroll
            for (int n = 0; n < NTILES; ++n)
                #pragma unroll
                for (int r = 0; r < 4; ++r) acc[n][r] += red[n * 4 + r];
        }
        const int r0 = (lane >> 4) * 4;
        const int cb = lane & 15;
        #pragma unroll
        for (int n = 0; n < 3; ++n)
            #pragma unroll
            for (int r = 0; r < 4; ++r)
                t_lds[r0 + r][n * 16 + cb] = acc[n][r];
        #pragma unroll
        for (int n = 3; n < 5; ++n)
            #pragma unroll
            for (int r = 0; r < 4; ++r)
                bc_out[(size_t)(mt * 16 + r0 + r) * 32 + (n - 3) * 16 + cb] = acc[n][r];
    }
    __syncthreads();

    // ---- phase B: 16 rows, d0 = tid (512), d1 = tid+512 (first 256) ----
    const int d0 = tid;
    const int d1 = tid + 512;
    const bool has2 = (tid < 256);

    float z0[16], z1[16];
    {
        float bb0 = b_dt[d0];
        float bb1 = has2 ? b_dt[d1] : 0.f;
        #pragma unroll
        for (int li = 0; li < 16; ++li) { z0[li] = bb0; z1[li] = bb1; }
    }
    #pragma unroll 2
    for (int r4 = 0; r4 < RNK; r4 += 4) {
        float w00 = W_dtp[(r4 + 0) * DD + d0];
        float w01 = W_dtp[(r4 + 1) * DD + d0];
        float w02 = W_dtp[(r4 + 2) * DD + d0];
        float w03 = W_dtp[(r4 + 3) * DD + d0];
        float w10 = has2 ? W_dtp[(r4 + 0) * DD + d1] : 0.f;
        float w11 = has2 ? W_dtp[(r4 + 1) * DD + d1] : 0.f;
        float w12 = has2 ? W_dtp[(r4 + 2) * DD + d1] : 0.f;
        float w13 = has2 ? W_dtp[(r4 + 3) * DD + d1] : 0.f;
        #pragma unroll
        for (int li = 0; li < 16; ++li) {
            float4 t4 = *(const float4*)&t_lds[li][r4];
            z0[li] = fmaf(t4.x, w00, z0[li]);
            z0[li] = fmaf(t4.y, w01, z0[li]);
            z0[li] = fmaf(t4.z, w02, z0[li]);
            z0[li] = fmaf(t4.w, w03, z0[li]);
            z1[li] = fmaf(t4.x, w10, z1[li]);
            z1[li] = fmaf(t4.y, w11, z1[li]);
            z1[li] = fmaf(t4.z, w12, z1[li]);
            z1[li] = fmaf(t4.w, w13, z1[li]);
        }
    }
    #pragma unroll
    for (int li = 0; li < 16; ++li) {
        z0[li] = softplus_f(z0[li]);
        z1[li] = has2 ? softplus_f(z1[li]) : 0.f;
    }
    #pragma unroll
    for (int li = 0; li < 16; ++li) {
        float ss = wave_sum(z0[li] * z0[li] + z1[li] * z1[li]);
        if (lane == 0) red2[wq][li] = ss;
    }
    __syncthreads();
    {
        float rs0 = rms_scale[d0];
        float rs1 = has2 ? rms_scale[d1] : 0.f;
        #pragma unroll
        for (int li = 0; li < 16; ++li) {
            float tot = 0.f;
            #pragma unroll
            for (int k = 0; k < 8; ++k) tot += red2[k][li];
            float inv = rsqrtf(tot * (1.0f / DD) + 1e-6f);
            size_t rowoff = (size_t)(mt * 16 + li) * DD;
            delta_out[rowoff + d0] = soft_clamp_f(z0[li] * inv * rs0);
            if (has2)
                delta_out[rowoff + d1] = soft_clamp_f(z1[li] * inv * rs1);
        }
    }
}

// ---------------------------------------------------------------------------
// Scan pass 1 (TCH=32, staged; sqrt(delta) in LDS; 1 rcp per step).
// ---------------------------------------------------------------------------
__global__ __launch_bounds__(256, 8) void k_scan1(
    const float* __restrict__ x, const float* __restrict__ delta,
    const float* __restrict__ bc, const float* __restrict__ A_log,
    float* __restrict__ Pbuf, float* __restrict__ Hbuf)
{
    __shared__ __align__(16) float xs[(TCH + 1) * 64];  // 8.25 KB
    __shared__ __align__(16) float sqv[TCH * 64];       // 8 KB
    __shared__ __align__(16) float bs[TCH * 16];        // 2 KB

    const int tid = threadIdx.x;
    const int db  = blockIdx.x * 64;
    const int c   = blockIdx.y;
    const int l0  = c * TCH;

    for (int i = tid; i < (TCH + 1) * 16; i += 256) {
        int r = i >> 4, f = i & 15;
        int l = l0 - 1 + r;
        float4 v = (l >= 0) ? *(const float4*)&x[(size_t)l * DD + db + f * 4]
                            : make_float4(0.f, 0.f, 0.f, 0.f);
        *(float4*)&xs[r * 64 + f * 4] = v;
    }
    for (int i = tid; i < TCH * 16; i += 256) {
        int r = i >> 4, f = i & 15;
        float4 v = *(const float4*)&delta[(size_t)(l0 + r) * DD + db + f * 4];
        v.x = sqrtf(v.x); v.y = sqrtf(v.y); v.z = sqrtf(v.z); v.w = sqrtf(v.w);
        *(float4*)&sqv[r * 64 + f * 4] = v;
    }
    if (tid < TCH * 4) {
        int r = tid >> 2, f = tid & 3;
        *(float4*)&bs[r * 16 + f * 4] =
            *(const float4*)&bc[(size_t)(l0 + r) * 32 + f * 4];
    }

    const int lane = tid & 63;
    const int w    = tid >> 6;
    const int q    = lane >> 4;
    const int dlo  = (lane & 15) + w * 16;
    const int d    = db + dlo;

    float An[4];
    {
        float4 a = *(const float4*)&A_log[d * NST + q * 4];
        An[0] = -expf(a.x); An[1] = -expf(a.y);
        An[2] = -expf(a.z); An[3] = -expf(a.w);
    }
    __syncthreads();

    float h[4]  = {0.f, 0.f, 0.f, 0.f};
    float Pp[4] = {1.f, 1.f, 1.f, 1.f};
    float xprev = xs[dlo];

    #pragma unroll 4
    for (int ll = 0; ll < TCH; ++ll) {
        float xv = xs[(ll + 1) * 64 + dlo];
        float sq = sqv[ll * 64 + dlo];
        float4 Bc = *(const float4*)&bs[ll * 16 + q * 4];

        float xin = 0.5f * (xv + xprev);
        xprev = xv;
        float c0 = 0.5f * sq * sq;
        float c1 = sq * xin;

        float dn0 = fmaf(-c0, An[0], 1.0f);
        float dn1 = fmaf(-c0, An[1], 1.0f);
        float dn2 = fmaf(-c0, An[2], 1.0f);
        float dn3 = fmaf(-c0, An[3], 1.0f);
        float m01 = dn0 * dn1, m23 = dn2 * dn3;
        float ip  = __builtin_amdgcn_rcpf(m01 * m23);
        float ip01 = ip * m23, ip23 = ip * m01;
        float iv0 = ip01 * dn1, iv1 = ip01 * dn0;
        float iv2 = ip23 * dn3, iv3 = ip23 * dn2;
        float t10 = 2.0f - dn0, t11 = 2.0f - dn1;
        float t12 = 2.0f - dn2, t13 = 2.0f - dn3;

        Pp[0] *= t10 * iv0;
        Pp[1] *= t11 * iv1;
        Pp[2] *= t12 * iv2;
        Pp[3] *= t13 * iv3;
        h[0] = fmaf(t10, h[0], c1 * Bc.x) * iv0;
        h[1] = fmaf(t11, h[1], c1 * Bc.y) * iv1;
        h[2] = fmaf(t12, h[2], c1 * Bc.z) * iv2;
        h[3] = fmaf(t13, h[3], c1 * Bc.w) * iv3;
    }
    #pragma unroll
    for (int n = 0; n < 4; ++n) {
        int idx = (c * NST + q * 4 + n) * DD + d;
        Pbuf[idx] = Pp[n];
        Hbuf[idx] = h[n];
    }
}

// ---------------------------------------------------------------------------
// Scan pass 2: serial thread-per-series, coalesced, 8-deep prefetch.
// ---------------------------------------------------------------------------
__global__ __launch_bounds__(64) void k_scan2(
    float* __restrict__ Pbuf, const float* __restrict__ Hbuf)
{
    const int s = blockIdx.x * 64 + threadIdx.x;
    const int d = s % DD;
    const int n = s / DD;
    const int stride = NST * DD;

    int idx = n * DD + d;
    int idx_pf = idx;
    float p[8], h[8];
    #pragma unroll
    for (int i = 0; i < 8; ++i) {
        p[i] = Pbuf[idx_pf];
        h[i] = Hbuf[idx_pf];
        idx_pf += stride;
    }

    float carry = 0.f;
    for (int g = 0; g < NCH / 8; ++g) {
        float pn[8], hn[8];
        if (g + 1 < NCH / 8) {
            #pragma unroll
            for (int i = 0; i < 8; ++i) {
                pn[i] = Pbuf[idx_pf];
                hn[i] = Hbuf[idx_pf];
                idx_pf += stride;
            }
        }
        #pragma unroll
        for (int i = 0; i < 8; ++i) {
            Pbuf[idx] = carry;
            carry = fmaf(p[i], carry, h[i]);
            idx += stride;
        }
        #pragma unroll
        for (int i = 0; i < 8; ++i) { p[i] = pn[i]; h[i] = hn[i]; }
    }
}

// ---------------------------------------------------------------------------
// Scan pass 3 (TCH=32, staged, sqrt-in-LDS, 1 rcp/step).
// ---------------------------------------------------------------------------
__global__ __launch_bounds__(256, 8) void k_scan3(
    const float* __restrict__ x, const float* __restrict__ delta,
    const float* __restrict__ bc, const float* __restrict__ A_log,
    const float* __restrict__ carryin, const float* __restrict__ D_param,
    float* __restrict__ out)
{
    __shared__ __align__(16) float xs[(TCH + 1) * 64];
    __shared__ __align__(16) float sqv[TCH * 64];
    __shared__ __align__(16) float bs[TCH * 32];

    const int tid = threadIdx.x;
    const int db  = blockIdx.x * 64;
    const int c   = blockIdx.y;
    const int l0  = c * TCH;

    for (int i = tid; i < (TCH + 1) * 16; i += 256) {
        int r = i >> 4, f = i & 15;
        int l = l0 - 1 + r;
        float4 v = (l >= 0) ? *(const float4*)&x[(size_t)l * DD + db + f * 4]
                            : make_float4(0.f, 0.f, 0.f, 0.f);
        *(float4*)&xs[r * 64 + f * 4] = v;
    }
    for (int i = tid; i < TCH * 16; i += 256) {
        int r = i >> 4, f = i & 15;
        float4 v = *(const float4*)&delta[(size_t)(l0 + r) * DD + db + f * 4];
        v.x = sqrtf(v.x); v.y = sqrtf(v.y); v.z = sqrtf(v.z); v.w = sqrtf(v.w);
        *(float4*)&sqv[r * 64 + f * 4] = v;
    }
    for (int i = tid; i < TCH * 8; i += 256) {
        int r = i >> 3, f = i & 7;
        *(float4*)&bs[r * 32 + f * 4] =
            *(const float4*)&bc[(size_t)(l0 + r) * 32 + f * 4];
    }

    const int lane = tid & 63;
    const int w    = tid >> 6;
    const int q    = lane >> 4;
    const int dlo  = (lane & 15) + w * 16;
    const int d    = db + dlo;

    float An[4];
    {
        float4 a = *(const float4*)&A_log[d * NST + q * 4];
        An[0] = -expf(a.x); An[1] = -expf(a.y);
        An[2] = -expf(a.z); An[3] = -expf(a.w);
    }
    float h[4];
    #pragma unroll
    for (int n = 0; n < 4; ++n)
        h[n] = carryin[(c * NST + q * 4 + n) * DD + d];
    const float Dp = D_param[d];

    __syncthreads();

    float xprev = xs[dlo];
    #pragma unroll 4
    for (int ll = 0; ll < TCH; ++ll) {
        float xv = xs[(ll + 1) * 64 + dlo];
        float sq = sqv[ll * 64 + dlo];
        float4 Bc = *(const float4*)&bs[ll * 32 + q * 4];
        float4 Cc = *(const float4*)&bs[ll * 32 + 16 + q * 4];

        float xin = 0.5f * (xv + xprev);
        xprev = xv;
        float c0 = 0.5f * sq * sq;
        float c1 = sq * xin;

        float dn0 = fmaf(-c0, An[0], 1.0f);
        float dn1 = fmaf(-c0, An[1], 1.0f);
        float dn2 = fmaf(-c0, An[2], 1.0f);
        float dn3 = fmaf(-c0, An[3], 1.0f);
        float m01 = dn0 * dn1, m23 = dn2 * dn3;
        float ip  = __builtin_amdgcn_rcpf(m01 * m23);
        float ip01 = ip * m23, ip23 = ip * m01;
        float iv0 = ip01 * dn1, iv1 = ip01 * dn0;
        float iv2 = ip23 * dn3, iv3 = ip23 * dn2;
        float t10 = 2.0f - dn0, t11 = 2.0f - dn1;
        float t12 = 2.0f - dn2, t13 = 2.0f - dn3;

        h[0] = fmaf(t10, h[0], c1 * Bc.x) * iv0;
        h[1] = fmaf(t11, h[1], c1 * Bc.y) * iv1;
        h[2] = fmaf(t12, h[2], c1 * Bc.z) * iv2;
        h[3] = fmaf(t13, h[3], c1 * Bc.w) * iv3;

        float y = h[0] * Cc.x;
        y = fmaf(h[1], Cc.y, y);
        y = fmaf(h[2], Cc.z, y);
        y = fmaf(h[3], Cc.w, y);

        y += __shfl_xor(y, 16, 64);
        y += __shfl_xor(y, 32, 64);
        if (q == 0)
            out[(size_t)(l0 + ll) * DD + d] = fmaf(Dp, xv, y);
    }
}

extern "C" void kernel_launch(void* const* d_in, const int* in_sizes, int n_in,
                              void* d_out, int out_size, void* d_ws, size_t ws_size,
                              hipStream_t stream) {
    const float* x         = (const float*)d_in[0];
    const float* A_log     = (const float*)d_in[1];
    const float* D_param   = (const float*)d_in[2];
    const float* W_bc      = (const float*)d_in[3];
    const float* W_dt      = (const float*)d_in[4];
    const float* W_dtp     = (const float*)d_in[5];
    const float* b_dt      = (const float*)d_in[6];
    const float* rms_scale = (const float*)d_in[7];
    float* out = (float*)d_out;

    float* ws    = (float*)d_ws;
    float* delta = ws;                               // L*D
    float* bcbuf = delta + (size_t)LSEQ * DD;        // L*32
    float* Pbuf  = bcbuf + (size_t)LSEQ * 32;        // NCH*16*D
    float* Hbuf  = Pbuf + (size_t)NCH * NST * DD;    // NCH*16*D
    unsigned short* wf_hi = (unsigned short*)(Hbuf + (size_t)NCH * NST * DD);
    unsigned short* wf_lo = wf_hi + WFRAG_N;

    k_prep<<<(WFRAG_N + 255) / 256, 256, 0, stream>>>(W_dt, W_bc, wf_hi, wf_lo);
    k_proj_mfma<<<LSEQ / 16, 512, 0, stream>>>(x, wf_hi, wf_lo, W_dtp, b_dt,
                                               rms_scale, delta, bcbuf);
    k_scan1<<<dim3(DD / 64, NCH), 256, 0, stream>>>(x, delta, bcbuf, A_log,
                                                    Pbuf, Hbuf);
    k_scan2<<<(DD * NST) / 64, 64, 0, stream>>>(Pbuf, Hbuf);
    k_scan3<<<dim3(DD / 64, NCH), 256, 0, stream>>>(x, delta, bcbuf, A_log,
                                                    Pbuf, D_param, out);
}